// Round 1
// baseline (202.816 us; speedup 1.0000x reference)
//
#include <hip/hip_runtime.h>
#include <math.h>

#define GRID_CELLS 49
#define NOBJ 10
#define BB 2
#define NCLS 20
#define OUT_C 30   // 5*BB + NCLS
#define LAMBDA_C 5.0f
#define LAMBDA_N 0.5f

__global__ __launch_bounds__(64) void yolo_loss_kernel(
    const float* __restrict__ outputs,
    const float* __restrict__ target,
    float* __restrict__ out,
    int batch, float inv_batch)
{
    __shared__ __align__(16) float row[GRID_CELLS * OUT_C]; // 1470 floats
    __shared__ float gt[GRID_CELLS][BB][5];                 // 490 floats
    __shared__ float tgts[NOBJ][5];
    __shared__ int   cellArr[NOBJ];
    __shared__ int   nzArr[NOBJ];

    const int tid = threadIdx.x;
    float acc = 0.0f;

    for (int b = blockIdx.x; b < batch; b += gridDim.x) {
        // ---- stage outputs row into LDS (coalesced float2: 735 elems) ----
        {
            const float2* src = reinterpret_cast<const float2*>(outputs + (size_t)b * (GRID_CELLS * OUT_C));
            float2* dst = reinterpret_cast<float2*>(row);
            #pragma unroll 6
            for (int i = tid; i < (GRID_CELLS * OUT_C) / 2; i += 64) dst[i] = src[i];
        }
        // ---- zero gt ----
        for (int i = tid; i < GRID_CELLS * BB * 5; i += 64) (&gt[0][0][0])[i] = 0.0f;
        // ---- load + preprocess targets (sqrt on dims 2:4, nan->-1) ----
        if (tid < NOBJ * 5) {
            float v = target[(size_t)b * NOBJ * 5 + tid];
            int d = tid % 5;
            if (d == 2 || d == 3) v = sqrtf(v);
            if (v != v) v = -1.0f;   // nan_to_num(nan=-1.0)
            (&tgts[0][0])[tid] = v;
        }
        __syncthreads();
        // ---- per-object cell / nonzero ----
        if (tid < NOBJ) {
            float x = tgts[tid][0];
            float y = tgts[tid][1];
            int xi = (int)truncf(7.0f * x);
            int yi = (int)truncf(7.0f * y);
            int cell = 7 * yi + xi;
            cell = cell < 0 ? 0 : (cell > GRID_CELLS - 1 ? GRID_CELLS - 1 : cell);
            bool valid = (x != -1.0f) && (xi >= 0);
            float s = tgts[tid][0] + tgts[tid][1] + tgts[tid][2] + tgts[tid][3] + tgts[tid][4];
            cellArr[tid] = cell;
            nzArr[tid]   = (valid && s > 0.0f) ? 1 : 0;
        }
        __syncthreads();
        // ---- slot assignment (cumsum of nonzero per cell), write gt ----
        if (tid < NOBJ && nzArr[tid]) {
            int c = cellArr[tid];
            int slot = 0;
            for (int o = 0; o < tid; ++o) slot += (nzArr[o] && cellArr[o] == c) ? 1 : 0;
            if (slot < BB) {
                #pragma unroll
                for (int d = 0; d < 5; ++d) gt[c][slot][d] = tgts[tid][d];
            }
        }
        __syncthreads();
        // ---- per-cell loss ----
        if (tid < GRID_CELLS) {
            const int c = tid;
            const float* r = &row[c * OUT_C];
            float pred[BB][5];
            #pragma unroll
            for (int p = 0; p < BB; ++p)
                #pragma unroll
                for (int d = 0; d < 5; ++d) pred[p][d] = r[p * 5 + d];

            float pminx[BB], pmaxx[BB], pminy[BB], pmaxy[BB], parea[BB];
            #pragma unroll
            for (int p = 0; p < BB; ++p) {
                float sw = sqrtf(pred[p][2]);
                float sh = sqrtf(pred[p][3]);
                float w2 = sw * sw, h2 = sh * sh;
                pminx[p] = pred[p][0] - w2; pmaxx[p] = pred[p][0] + w2;
                pminy[p] = pred[p][1] - h2; pmaxy[p] = pred[p][1] + h2;
                parea[p] = fabsf(pmaxx[p] - pminx[p]) * fabsf(pmaxy[p] - pminy[p]);
            }
            float g[BB][5];
            #pragma unroll
            for (int s = 0; s < BB; ++s)
                #pragma unroll
                for (int d = 0; d < 5; ++d) g[s][d] = gt[c][s][d];

            float gminx[BB], gmaxx[BB], gminy[BB], gmaxy[BB], garea[BB];
            #pragma unroll
            for (int s = 0; s < BB; ++s) {
                float w2 = g[s][2] * g[s][2], h2 = g[s][3] * g[s][3];
                gminx[s] = g[s][0] - w2; gmaxx[s] = g[s][0] + w2;
                gminy[s] = g[s][1] - h2; gmaxy[s] = g[s][1] + h2;
                garea[s] = fabsf(gmaxx[s] - gminx[s]) * fabsf(gmaxy[s] - gminy[s]);
            }
            // t_index[s] = argmax_p iou[p][s]  (first max on ties, as jnp.argmax)
            int t_index[BB];
            #pragma unroll
            for (int s = 0; s < BB; ++s) {
                float best = 0.0f; int bi = 0;
                #pragma unroll
                for (int p = 0; p < BB; ++p) {
                    float ix0 = fmaxf(gminx[s], pminx[p]);
                    float iy0 = fmaxf(gminy[s], pminy[p]);
                    float ix1 = fminf(gmaxx[s], pmaxx[p]);
                    float iy1 = fminf(gmaxy[s], pmaxy[p]);
                    float dx = fmaxf(ix1 - ix0, 0.0f);
                    float dy = fmaxf(iy1 - iy0, 0.0f);
                    float inter = dx * dy;
                    float uni = garea[s] + parea[p] - inter;
                    float iou = (uni == 0.0f) ? 0.0f : inter / uni;
                    if (p == 0) { best = iou; bi = 0; }
                    else if (iou > best) { best = iou; bi = p; }
                }
                t_index[s] = bi;
            }
            // class max/argmax over 20 scores (first max on ties)
            float maxp = r[5 * BB]; int cls = 0;
            #pragma unroll
            for (int k = 1; k < NCLS; ++k) {
                float v = r[5 * BB + k];
                if (v > maxp) { maxp = v; cls = k; }
            }
            float fcls = (float)cls;

            float lsum = 0.0f;
            #pragma unroll
            for (int s = 0; s < BB; ++s) {
                float ga[5];
                #pragma unroll
                for (int d = 0; d < 5; ++d) ga[d] = g[t_index[s]][d];
                // conf (trunc-based IoU of raw boxes)
                float r1w = pred[s][2] * pred[s][2], r1h = pred[s][3] * pred[s][3];
                float r2w = ga[2] * ga[2],           r2h = ga[3] * ga[3];
                float min1x = pred[s][0] - 0.5f * r1w, max1x = pred[s][0] + 0.5f * r1w;
                float min1y = pred[s][1] - 0.5f * r1h, max1y = pred[s][1] + 0.5f * r1h;
                float min2x = ga[0] - 0.5f * r2w, max2x = ga[0] + 0.5f * r2w;
                float min2y = ga[1] - 0.5f * r2h, max2y = ga[1] + 0.5f * r2h;
                float dx = fmaxf(fminf(max1x, max2x) - fmaxf(min1x, min2x), 0.0f);
                float dy = fmaxf(fminf(max1y, max2y) - fmaxf(min1y, min2y), 0.0f);
                float inter2 = dx * dy;
                float uni2 = r1w * r1h + r2w * r2h - inter2;
                float conf;
                if (truncf(uni2) == 0.0f || truncf(inter2) == 0.0f) conf = 0.0f;
                else conf = truncf(inter2 / (uni2 == 0.0f ? 1.0f : uni2));
                // obj loss: w=[5,5,5,5,1] * (final_gt - pred5)^2
                #pragma unroll
                for (int d = 0; d < 4; ++d) {
                    float df = ga[d] - pred[s][d];
                    lsum += LAMBDA_C * df * df;
                }
                { float df = conf - pred[s][4]; lsum += df * df; }
                // noobj loss (mask quirk: last batch item, slot t_index[BB-1] zeroed)
                float m = 1.0f;
                if (b == batch - 1 && s == t_index[BB - 1]) m = 0.0f;
                float dn = (pred[s][4] - conf) * m;
                lsum += LAMBDA_N * dn * dn;
                // class loss
                float predn = maxp * pred[s][4];
                float truth = (conf == fcls) ? 1.0f : 0.0f;
                float sum5 = ga[0] + ga[1] + ga[2] + ga[3] + conf;
                float cm = (sum5 > 0.0f) ? 1.0f : ((sum5 < 0.0f) ? -1.0f : 0.0f);
                float dcl = truth - predn;
                lsum += cm * dcl * dcl;
            }
            acc += lsum;
        }
        __syncthreads(); // protect LDS reuse across batch-item iterations
    }

    // wave (64-lane) reduction, one atomic per block
    float v = acc;
    #pragma unroll
    for (int off = 32; off > 0; off >>= 1) v += __shfl_down(v, off, 64);
    if (tid == 0) atomicAdd(out, v * inv_batch);
}

extern "C" void kernel_launch(void* const* d_in, const int* in_sizes, int n_in,
                              void* d_out, int out_size, void* d_ws, size_t ws_size,
                              hipStream_t stream) {
    const float* outputs = (const float*)d_in[0];
    const float* target  = (const float*)d_in[1];
    float* out = (float*)d_out;
    int batch = in_sizes[1] / (NOBJ * 5);   // 16384
    hipMemsetAsync(out, 0, sizeof(float), stream);
    int nblocks = batch < 4096 ? batch : 4096;
    yolo_loss_kernel<<<nblocks, 64, 0, stream>>>(outputs, target, out, batch, 1.0f / (float)batch);
}

// Round 2
// 153.086 us; speedup vs baseline: 1.3249x; 1.3249x over previous
//
#include <hip/hip_runtime.h>
#include <math.h>

#define GRID_CELLS 49
#define NOBJ 10
#define BB 2
#define NCLS 20
#define OUT_C 30   // 5*BB + NCLS
#define LAMBDA_C 5.0f
#define LAMBDA_N 0.5f
#define BLOCK 256

// One thread per (batch_item, grid_cell). No syncthreads in hot path.
__global__ __launch_bounds__(BLOCK) void yolo_loss_flat(
    const float* __restrict__ outputs,
    const float* __restrict__ target,
    float* __restrict__ partial,
    int batch)
{
    const int gid = blockIdx.x * BLOCK + threadIdx.x;
    const int total = batch * GRID_CELLS;
    float lsum = 0.0f;

    if (gid < total) {
        const int b = gid / GRID_CELLS;
        const int c = gid - b * GRID_CELLS;

        // ---- phase 1: build gt[2][5] for this cell from 10 targets ----
        // load 50 target floats as 25 float2 (row base b*200B is 8-aligned)
        float tv[NOBJ * 5];
        {
            const float2* t2 = reinterpret_cast<const float2*>(target + (size_t)b * (NOBJ * 5));
            #pragma unroll
            for (int i = 0; i < (NOBJ * 5) / 2; ++i) {
                float2 v = t2[i];
                tv[2 * i]     = v.x;
                tv[2 * i + 1] = v.y;
            }
        }
        float g0[5] = {0.f, 0.f, 0.f, 0.f, 0.f};
        float g1[5] = {0.f, 0.f, 0.f, 0.f, 0.f};
        int cnt = 0;
        #pragma unroll
        for (int o = 0; o < NOBJ; ++o) {
            float t0 = tv[o * 5 + 0];
            float t1 = tv[o * 5 + 1];
            float t2 = sqrtf(tv[o * 5 + 2]);
            float t3 = sqrtf(tv[o * 5 + 3]);
            float t4 = tv[o * 5 + 4];
            if (t0 != t0) t0 = -1.0f;
            if (t1 != t1) t1 = -1.0f;
            if (t2 != t2) t2 = -1.0f;
            if (t3 != t3) t3 = -1.0f;
            if (t4 != t4) t4 = -1.0f;
            int xi = (int)truncf(7.0f * t0);
            int yi = (int)truncf(7.0f * t1);
            int cell = 7 * yi + xi;
            cell = cell < 0 ? 0 : (cell > GRID_CELLS - 1 ? GRID_CELLS - 1 : cell);
            bool valid = (t0 != -1.0f) && (xi >= 0);
            float s5 = t0 + t1 + t2 + t3 + t4;
            bool nz = valid && (s5 > 0.0f);
            if (nz && cell == c) {
                if (cnt == 0) { g0[0]=t0; g0[1]=t1; g0[2]=t2; g0[3]=t3; g0[4]=t4; }
                else if (cnt == 1) { g1[0]=t0; g1[1]=t1; g1[2]=t2; g1[3]=t3; g1[4]=t4; }
                ++cnt;
            }
        }
        float g[BB][5];
        #pragma unroll
        for (int d = 0; d < 5; ++d) { g[0][d] = g0[d]; g[1][d] = g1[d]; }

        // ---- phase 2: load this cell's 30 output floats (15x float2) ----
        float vals[OUT_C];
        {
            const float2* r2 = reinterpret_cast<const float2*>(outputs + (size_t)gid * OUT_C);
            #pragma unroll
            for (int i = 0; i < OUT_C / 2; ++i) {
                float2 v = r2[i];
                vals[2 * i]     = v.x;
                vals[2 * i + 1] = v.y;
            }
        }
        float pred[BB][5];
        #pragma unroll
        for (int p = 0; p < BB; ++p)
            #pragma unroll
            for (int d = 0; d < 5; ++d) pred[p][d] = vals[p * 5 + d];

        // pred boxes (sqrt-then-square, matching reference bit behavior)
        float pminx[BB], pmaxx[BB], pminy[BB], pmaxy[BB], parea[BB];
        #pragma unroll
        for (int p = 0; p < BB; ++p) {
            float sw = sqrtf(pred[p][2]);
            float sh = sqrtf(pred[p][3]);
            float w2 = sw * sw, h2 = sh * sh;
            pminx[p] = pred[p][0] - w2; pmaxx[p] = pred[p][0] + w2;
            pminy[p] = pred[p][1] - h2; pmaxy[p] = pred[p][1] + h2;
            parea[p] = fabsf(pmaxx[p] - pminx[p]) * fabsf(pmaxy[p] - pminy[p]);
        }
        float gminx[BB], gmaxx[BB], gminy[BB], gmaxy[BB], garea[BB];
        #pragma unroll
        for (int s = 0; s < BB; ++s) {
            float w2 = g[s][2] * g[s][2], h2 = g[s][3] * g[s][3];
            gminx[s] = g[s][0] - w2; gmaxx[s] = g[s][0] + w2;
            gminy[s] = g[s][1] - h2; gmaxy[s] = g[s][1] + h2;
            garea[s] = fabsf(gmaxx[s] - gminx[s]) * fabsf(gmaxy[s] - gminy[s]);
        }
        // t_index[s] = argmax_p iou[p][s] (first max on ties, as jnp.argmax)
        int t_index[BB];
        #pragma unroll
        for (int s = 0; s < BB; ++s) {
            float best = 0.0f; int bi = 0;
            #pragma unroll
            for (int p = 0; p < BB; ++p) {
                float ix0 = fmaxf(gminx[s], pminx[p]);
                float iy0 = fmaxf(gminy[s], pminy[p]);
                float ix1 = fminf(gmaxx[s], pmaxx[p]);
                float iy1 = fminf(gmaxy[s], pmaxy[p]);
                float dx = fmaxf(ix1 - ix0, 0.0f);
                float dy = fmaxf(iy1 - iy0, 0.0f);
                float inter = dx * dy;
                float uni = garea[s] + parea[p] - inter;
                float iou = (uni == 0.0f) ? 0.0f : inter / uni;
                if (p == 0) { best = iou; bi = 0; }
                else if (iou > best) { best = iou; bi = p; }
            }
            t_index[s] = bi;
        }
        // class max/argmax over 20 scores (first max on ties)
        float maxp = vals[5 * BB]; int cls = 0;
        #pragma unroll
        for (int k = 1; k < NCLS; ++k) {
            float v = vals[5 * BB + k];
            if (v > maxp) { maxp = v; cls = k; }
        }
        float fcls = (float)cls;

        #pragma unroll
        for (int s = 0; s < BB; ++s) {
            float ga[5];
            #pragma unroll
            for (int d = 0; d < 5; ++d) ga[d] = (t_index[s] == 0) ? g[0][d] : g[1][d];
            // conf (trunc-based IoU of raw boxes)
            float r1w = pred[s][2] * pred[s][2], r1h = pred[s][3] * pred[s][3];
            float r2w = ga[2] * ga[2],           r2h = ga[3] * ga[3];
            float min1x = pred[s][0] - 0.5f * r1w, max1x = pred[s][0] + 0.5f * r1w;
            float min1y = pred[s][1] - 0.5f * r1h, max1y = pred[s][1] + 0.5f * r1h;
            float min2x = ga[0] - 0.5f * r2w, max2x = ga[0] + 0.5f * r2w;
            float min2y = ga[1] - 0.5f * r2h, max2y = ga[1] + 0.5f * r2h;
            float dx = fmaxf(fminf(max1x, max2x) - fmaxf(min1x, min2x), 0.0f);
            float dy = fmaxf(fminf(max1y, max2y) - fmaxf(min1y, min2y), 0.0f);
            float inter2 = dx * dy;
            float uni2 = r1w * r1h + r2w * r2h - inter2;
            float conf;
            if (truncf(uni2) == 0.0f || truncf(inter2) == 0.0f) conf = 0.0f;
            else conf = truncf(inter2 / (uni2 == 0.0f ? 1.0f : uni2));
            // obj loss: w=[5,5,5,5,1] * (final_gt - pred5)^2
            #pragma unroll
            for (int d = 0; d < 4; ++d) {
                float df = ga[d] - pred[s][d];
                lsum += LAMBDA_C * df * df;
            }
            { float df = conf - pred[s][4]; lsum += df * df; }
            // noobj loss (mask quirk: last batch item, slot t_index[BB-1] zeroed)
            float m = 1.0f;
            if (b == batch - 1 && s == t_index[BB - 1]) m = 0.0f;
            float dn = (pred[s][4] - conf) * m;
            lsum += LAMBDA_N * dn * dn;
            // class loss
            float predn = maxp * pred[s][4];
            float truth = (conf == fcls) ? 1.0f : 0.0f;
            float sum5 = ga[0] + ga[1] + ga[2] + ga[3] + conf;
            float cm = (sum5 > 0.0f) ? 1.0f : ((sum5 < 0.0f) ? -1.0f : 0.0f);
            float dcl = truth - predn;
            lsum += cm * dcl * dcl;
        }
    }

    // ---- block reduction: wave shuffle -> LDS -> one partial per block ----
    #pragma unroll
    for (int off = 32; off > 0; off >>= 1) lsum += __shfl_down(lsum, off, 64);
    __shared__ float red[BLOCK / 64];
    const int wid = threadIdx.x >> 6;
    const int lane = threadIdx.x & 63;
    if (lane == 0) red[wid] = lsum;
    __syncthreads();
    if (threadIdx.x == 0) {
        float s = 0.0f;
        #pragma unroll
        for (int w = 0; w < BLOCK / 64; ++w) s += red[w];
        partial[blockIdx.x] = s;
    }
}

__global__ __launch_bounds__(256) void reduce_partials(
    const float* __restrict__ partial, int n, float* __restrict__ out, float inv_batch)
{
    float s = 0.0f;
    for (int i = threadIdx.x; i < n; i += 256) s += partial[i];
    #pragma unroll
    for (int off = 32; off > 0; off >>= 1) s += __shfl_down(s, off, 64);
    __shared__ float red[4];
    const int wid = threadIdx.x >> 6;
    const int lane = threadIdx.x & 63;
    if (lane == 0) red[wid] = s;
    __syncthreads();
    if (threadIdx.x == 0) out[0] = (red[0] + red[1] + red[2] + red[3]) * inv_batch;
}

extern "C" void kernel_launch(void* const* d_in, const int* in_sizes, int n_in,
                              void* d_out, int out_size, void* d_ws, size_t ws_size,
                              hipStream_t stream) {
    const float* outputs = (const float*)d_in[0];
    const float* target  = (const float*)d_in[1];
    float* out = (float*)d_out;
    float* partial = (float*)d_ws;
    int batch = in_sizes[1] / (NOBJ * 5);   // 16384
    int total = batch * GRID_CELLS;
    int nblocks = (total + BLOCK - 1) / BLOCK;   // 3136
    yolo_loss_flat<<<nblocks, BLOCK, 0, stream>>>(outputs, target, partial, batch);
    reduce_partials<<<1, 256, 0, stream>>>(partial, nblocks, out, 1.0f / (float)batch);
}